// Round 24
// baseline (225.596 us; speedup 1.0000x reference)
//
#include <hip/hip_runtime.h>
#include <hip/hip_bf16.h>
#include <stdint.h>
#include <math.h>

#define NN 50000
#define DD 128
#define EE 500000
#define ROWT 1563   // ceil(NN/32)
#define NBIN 98     // ceil(NN/512) coarse bins
#define CHB 245     // ceil(EE/2048)

typedef __attribute__((ext_vector_type(8))) short bfx8;
typedef __attribute__((ext_vector_type(4))) short bfx4;
typedef __attribute__((ext_vector_type(4))) float f32x4;
typedef __attribute__((ext_vector_type(4))) int i32x4;
typedef unsigned short u16;

static __device__ __forceinline__ short f2bf(float f) {
  union { float f; uint32_t u; } v; v.f = f;
  uint32_t r = (v.u + 0x7fffu + ((v.u >> 16) & 1u)) >> 16;
  return (short)r;
}
static __device__ __forceinline__ float bf2f(short b) {
  union { uint32_t u; float f; } v; v.u = ((uint32_t)(uint16_t)b) << 16;
  return v.f;
}

// async global->LDS, 16B per lane; LDS dest = wave-uniform base + lane*16
static __device__ __forceinline__ void gl_lds16(const short* g, short* l) {
  __builtin_amdgcn_global_load_lds(
      (const __attribute__((address_space(1))) unsigned int*)g,
      (__attribute__((address_space(3))) unsigned int*)l, 16, 0, 0);
}

// B-fragment from packed weights: [ct][ks][64 lanes][8]
static __device__ __forceinline__ bfx8 load_pk(const short* p, int ct, int ks, int lane) {
  return *reinterpret_cast<const bfx8*>(p + ((((size_t)ct * 4 + ks) * 64 + lane) << 3));
}

// ---------------- prep: convert(0,1) | comb(2..7) | pack Ws(8..10) | chist(11..13) ----------------
struct PrepArgs {
  const float* csrc[2]; short* cdst[2];
  const float* A[6]; const float* B[6]; short* pout[6];
  const float* psrc[3]; short* pdst[3];
  const int* edge[3]; int* ccnt;
};

__global__ __launch_bounds__(256) void k_prep(PrepArgs p) {
  const int y = blockIdx.y;
  if (y < 2) {
    int i = (blockIdx.x * 256 + threadIdx.x) * 4;
    if (i >= NN * DD) return;
    f32x4 v = *reinterpret_cast<const f32x4*>(p.csrc[y] + i);
    bfx4 o;
    o[0]=f2bf(v[0]); o[1]=f2bf(v[1]); o[2]=f2bf(v[2]); o[3]=f2bf(v[3]);
    *reinterpret_cast<bfx4*>(p.cdst[y] + i) = o;
  } else if (y < 8) {
    if (blockIdx.x >= 192) return;
    const int e = y - 2;
    const float* A = p.A[e];
    const float* B = p.B[e];
    int tid = blockIdx.x * 256 + threadIdx.x;   // 49152 = 384*128
    int i = tid >> 7, j = tid & 127;            // P[i][j]
    float acc = 0.f;
    #pragma unroll 4
    for (int k = 0; k < 128; ++k) acc += A[i * 128 + k] * B[k * 128 + j];
    int ct = i >> 4;
    int lane = (i & 15) | ((((j & 31) >> 3)) << 4);
    int ks = j >> 5;
    int elem = j & 7;
    p.pout[e][(((size_t)(ct * 4 + ks) * 64 + lane) << 3) + elem] = f2bf(acc);
  } else if (y < 11) {
    if (blockIdx.x >= 8) return;
    const int jb = y - 8;
    int tid = blockIdx.x * 256 + threadIdx.x;   // < 2048 (nct=8)
    int lane = tid & 63, ks = (tid >> 6) & 3, ct = tid >> 8;
    const float* s = p.psrc[jb] + (size_t)(ct * 16 + (lane & 15)) * 128 + ks * 32 + ((lane >> 4) << 3);
    bfx8 o;
    #pragma unroll
    for (int i = 0; i < 8; ++i) o[i] = f2bf(s[i]);
    *reinterpret_cast<bfx8*>(p.pdst[jb] + ((size_t)tid << 3)) = o;
  } else {
    // coarse hist with LDS pre-aggregation
    if (blockIdx.x >= CHB) return;
    const int t = y - 11, tid = threadIdx.x;
    __shared__ int cnt[NBIN];
    for (int b = tid; b < NBIN; b += 256) cnt[b] = 0;
    __syncthreads();
    const int* ed = p.edge[t];
    int base = blockIdx.x * 2048;
    #pragma unroll
    for (int m = 0; m < 8; ++m) {
      int i = base + m * 256 + tid;
      if (i < EE) atomicAdd(&cnt[ed[EE + i] >> 9], 1);
    }
    __syncthreads();
    for (int b = tid; b < NBIN; b += 256)
      if (cnt[b]) atomicAdd(&p.ccnt[t * NBIN + b], cnt[b]);
  }
}

// ---------------- CSR build via two-level counting sort ----------------
struct CsrArgs {
  const int* edge[3];
  int* ccnt;      // [3][NBIN]
  int* cstart;    // [3][NBIN]
  int* ccur;      // [3][NBIN]
  uint32_t* cbkt[3];
  int* offs[3];
  u16* bucket[3];
};

// coarse scan: 3 types x NBIN (tiny)
__global__ __launch_bounds__(384) void k_cscan(CsrArgs a) {
  __shared__ int buf[3][128];
  int ty = threadIdx.x >> 7;       // 0..2
  int i = threadIdx.x & 127;
  int v = (i < NBIN) ? a.ccnt[ty * NBIN + i] : 0;
  buf[ty][i] = v;
  __syncthreads();
  for (int off = 1; off < 128; off <<= 1) {
    int tv = (i >= off) ? buf[ty][i - off] : 0;
    __syncthreads();
    buf[ty][i] += tv;
    __syncthreads();
  }
  if (i < NBIN) {
    int excl = buf[ty][i] - v;
    a.cstart[ty * NBIN + i] = excl;
    a.ccur[ty * NBIN + i] = excl;
  }
}

// coarse bin: per-block LDS count -> reserve -> burst write u32 entries
__global__ __launch_bounds__(256) void k_cbin(CsrArgs a) {
  const int t = blockIdx.y, tid = threadIdx.x;
  __shared__ int cnt[NBIN], cur[NBIN];
  for (int b = tid; b < NBIN; b += 256) cnt[b] = 0;
  __syncthreads();
  const int* ed = a.edge[t];
  int base = blockIdx.x * 4096;
  #pragma unroll
  for (int m = 0; m < 16; ++m) {
    int i = base + m * 256 + tid;
    if (i < EE) atomicAdd(&cnt[ed[EE + i] >> 9], 1);
  }
  __syncthreads();
  for (int b = tid; b < NBIN; b += 256)
    cur[b] = cnt[b] ? atomicAdd(&a.ccur[t * NBIN + b], cnt[b]) : 0;
  __syncthreads();
  uint32_t* cb = a.cbkt[t];
  #pragma unroll
  for (int m = 0; m < 16; ++m) {
    int i = base + m * 256 + tid;
    if (i < EE) {
      int tg = ed[EE + i];
      int b = tg >> 9;
      int pos = atomicAdd(&cur[b], 1);
      cb[pos] = (uint32_t)ed[i] | ((uint32_t)(tg & 511) << 20);
    }
  }
}

// fine sort: one block per coarse bin; counting sort by row; writes offs + u16 bucket
__global__ __launch_bounds__(256) void k_fsort(CsrArgs a) {
  const int t = blockIdx.y, bin = blockIdx.x, tid = threadIdx.x;
  __shared__ int rc[512], rcur[512], sb[256];
  int s0 = a.cstart[t * NBIN + bin];
  int cntb = a.ccnt[t * NBIN + bin];
  rc[tid] = 0; rc[tid + 256] = 0;
  __syncthreads();
  const uint32_t* cb = a.cbkt[t];
  for (int i = tid; i < cntb; i += 256) atomicAdd(&rc[cb[s0 + i] >> 20], 1);
  __syncthreads();
  int A = rc[2 * tid], B = rc[2 * tid + 1], s = A + B;
  sb[tid] = s;
  __syncthreads();
  for (int off = 1; off < 256; off <<= 1) {
    int v = (tid >= off) ? sb[tid - off] : 0;
    __syncthreads();
    sb[tid] += v;
    __syncthreads();
  }
  int excl = sb[tid] - s;
  rcur[2 * tid] = s0 + excl;
  rcur[2 * tid + 1] = s0 + excl + A;
  int rows0 = bin << 9;
  int nr = NN - rows0; if (nr > 512) nr = 512;
  if (2 * tid < nr)     a.offs[t][rows0 + 2 * tid]     = s0 + excl + A;
  if (2 * tid + 1 < nr) a.offs[t][rows0 + 2 * tid + 1] = s0 + excl + A + B;
  __syncthreads();
  u16* fb = a.bucket[t];
  for (int i = tid; i < cntb; i += 256) {
    uint32_t e = cb[s0 + i];
    int pos = atomicAdd(&rcur[e >> 20], 1);
    fb[pos] = (u16)e;          // src < 50000 < 2^16
  }
}

// ---------------- gather: aggX[row] = sum of x rows (bf16 out, deep unroll) ----------------
struct GArgs {
  const int* offs[3]; const u16* bkt[3];
  const short* xsrc[3]; short* agg[3];
};

__global__ __launch_bounds__(256) void k_gather(GArgs a) {
  const int ty = blockIdx.y;
  const int* __restrict__ offs = a.offs[ty];
  const u16* __restrict__ bucket = a.bkt[ty];
  const short* __restrict__ xsrc = a.xsrc[ty];
  short* __restrict__ agg = a.agg[ty];
  int tid = threadIdx.x;
  int row = blockIdx.x * 32 + (tid >> 3);
  if (row >= NN) return;
  int c0 = (tid & 7) * 16;
  int start = row ? offs[row - 1] : 0;
  int end = offs[row];
  f32x4 s0 = (f32x4)(0.f), s1 = (f32x4)(0.f), s2 = (f32x4)(0.f), s3 = (f32x4)(0.f);
  int i = start;
  for (; i + 8 <= end; i += 8) {
    const short* pp[8];
    #pragma unroll
    for (int m = 0; m < 8; ++m) pp[m] = xsrc + (size_t)bucket[i + m] * DD + c0;
    #pragma unroll
    for (int m = 0; m < 8; ++m) {
      bfx8 u = *reinterpret_cast<const bfx8*>(pp[m]);
      bfx8 v = *reinterpret_cast<const bfx8*>(pp[m] + 8);
      #pragma unroll
      for (int j = 0; j < 4; ++j) {
        s0[j] += bf2f(u[j]); s1[j] += bf2f(u[4+j]);
        s2[j] += bf2f(v[j]); s3[j] += bf2f(v[4+j]);
      }
    }
  }
  for (; i + 4 <= end; i += 4) {
    const short* pp[4];
    #pragma unroll
    for (int m = 0; m < 4; ++m) pp[m] = xsrc + (size_t)bucket[i + m] * DD + c0;
    #pragma unroll
    for (int m = 0; m < 4; ++m) {
      bfx8 u = *reinterpret_cast<const bfx8*>(pp[m]);
      bfx8 v = *reinterpret_cast<const bfx8*>(pp[m] + 8);
      #pragma unroll
      for (int j = 0; j < 4; ++j) {
        s0[j] += bf2f(u[j]); s1[j] += bf2f(u[4+j]);
        s2[j] += bf2f(v[j]); s3[j] += bf2f(v[4+j]);
      }
    }
  }
  for (; i < end; ++i) {
    const short* p = xsrc + (size_t)bucket[i] * DD + c0;
    bfx8 u = *reinterpret_cast<const bfx8*>(p), v = *reinterpret_cast<const bfx8*>(p + 8);
    #pragma unroll
    for (int j = 0; j < 4; ++j) {
      s0[j] += bf2f(u[j]); s1[j] += bf2f(u[4+j]);
      s2[j] += bf2f(v[j]); s3[j] += bf2f(v[4+j]);
    }
  }
  short* d = agg + (size_t)row * DD + c0;
  bfx8 o0, o1;
  #pragma unroll
  for (int j = 0; j < 4; ++j) {
    o0[j] = f2bf(s0[j]); o0[4+j] = f2bf(s1[j]);
    o1[j] = f2bf(s2[j]); o1[4+j] = f2bf(s3[j]);
  }
  *reinterpret_cast<bfx8*>(d) = o0;
  *reinterpret_cast<bfx8*>(d + 8) = o1;
}

// ---------------- GRU math + unit helpers ----------------
static __device__ __forceinline__ void gru8(const f32x4 h[2], const f32x4 ai[2][3],
                                            const f32x4 ah[2][3],
                                            float bir, float biz, float bin,
                                            float bhr, float bhz, float bhn,
                                            f32x4 res[2]) {
  #pragma unroll
  for (int rf = 0; rf < 2; ++rf)
    #pragma unroll
    for (int q = 0; q < 4; ++q) {
      float ir = ai[rf][0][q] + bir, iz = ai[rf][1][q] + biz, in = ai[rf][2][q] + bin;
      float hr = ah[rf][0][q] + bhr, hz = ah[rf][1][q] + bhz, hn = ah[rf][2][q] + bhn;
      float rr = __builtin_amdgcn_rcpf(1.f + __expf(-(ir + hr)));
      float zz = __builtin_amdgcn_rcpf(1.f + __expf(-(iz + hz)));
      float t2 = in + rr * hn;
      float nn = 1.f - 2.f * __builtin_amdgcn_rcpf(__expf(2.f * t2) + 1.f);   // tanh
      res[rf][q] = (1.f - zz) * nn + zz * h[rf][q];
    }
}

static __device__ __forceinline__ void gru_unit(
    const short* lds, int gbase, int ctw, int lane,
    const short* wsp, const short* combp, const short* whhsp,
    f32x4 (&h)[2], f32x4 (&ai)[2][3], f32x4 (&ah)[2][3]) {
  #pragma unroll
  for (int rf = 0; rf < 2; ++rf) {
    h[rf] = (f32x4)(0.f);
    #pragma unroll
    for (int g = 0; g < 3; ++g) { ai[rf][g] = (f32x4)(0.f); ah[rf][g] = (f32x4)(0.f); }
  }
  #pragma unroll
  for (int ks = 0; ks < 4; ++ks) {
    bfx8 x0 = *reinterpret_cast<const bfx8*>(lds + (0 + ks) * 512 + lane * 8);
    bfx8 x1 = *reinterpret_cast<const bfx8*>(lds + (4 + ks) * 512 + lane * 8);
    bfx8 g0 = *reinterpret_cast<const bfx8*>(lds + (gbase + ks) * 512 + lane * 8);
    bfx8 g1 = *reinterpret_cast<const bfx8*>(lds + (gbase + 4 + ks) * 512 + lane * 8);
    bfx8 bws = load_pk(wsp, ctw, ks, lane);
    h[0] = __builtin_amdgcn_mfma_f32_16x16x32_bf16(g0, bws, h[0], 0, 0, 0);
    h[1] = __builtin_amdgcn_mfma_f32_16x16x32_bf16(g1, bws, h[1], 0, 0, 0);
    #pragma unroll
    for (int g = 0; g < 3; ++g) {
      int ct = g * 8 + ctw;
      bfx8 bi = load_pk(combp, ct, ks, lane);
      bfx8 bh = load_pk(whhsp, ct, ks, lane);
      ai[0][g] = __builtin_amdgcn_mfma_f32_16x16x32_bf16(x0, bi, ai[0][g], 0, 0, 0);
      ai[1][g] = __builtin_amdgcn_mfma_f32_16x16x32_bf16(x1, bi, ai[1][g], 0, 0, 0);
      ah[0][g] = __builtin_amdgcn_mfma_f32_16x16x32_bf16(g0, bh, ah[0][g], 0, 0, 0);
      ah[1][g] = __builtin_amdgcn_mfma_f32_16x16x32_bf16(g1, bh, ah[1][g], 0, 0, 0);
    }
  }
}

// ---------------- merged ggru: blocks [0, ROWT) = e2+e3 serial -> out_a; [ROWT, 2*ROWT) = e1 -> out_b ----------------
struct GGArgs {
  const short* agg1; const short* agg2; const short* agg3;
  const short* xa; const short* xb;
  const short* wsp1; const short* combp1; const short* whhsp1;
  const short* wsp2; const short* combp2; const short* whhsp2;
  const short* wsp3; const short* combp3; const short* whhsp3;
  const float* bih1; const float* bhh1;
  const float* bih2; const float* bhh2;
  const float* bih3; const float* bhh3;
  float* out_a; float* out_b;
};

__global__ __launch_bounds__(512) void k_ggru(GGArgs a) {
  __shared__ short lds[24 * 512];
  const int wave = threadIdx.x >> 6, lane = threadIdx.x & 63;
  const int bx = blockIdx.x;
  const int ctw = wave;                // 0..7 (full 128 cols per block)
  const int col = ctw * 16 + (lane & 15);
  const int lq = (lane >> 4) << 2;

  if (bx < ROWT) {
    // ---- e2 then e3 (serial per wave), stage once -> out_a ----
    const int rbase = bx * 32;

    #pragma unroll
    for (int i = 0; i < 3; ++i) {
      int f = wave * 3 + i;
      const short* src = (f < 8) ? a.xa : ((f < 16) ? a.agg2 : a.agg3);
      int r = rbase + ((f >> 2) & 1) * 16 + (lane & 15);
      if (r >= NN) r = NN - 1;
      gl_lds16(src + (size_t)r * DD + (f & 3) * 32 + ((lane >> 4) << 3), lds + f * 512);
    }
    __syncthreads();

    f32x4 res2[2];
    {
      f32x4 h[2], ai[2][3], ah[2][3];
      gru_unit(lds, 8, ctw, lane, a.wsp2, a.combp2, a.whhsp2, h, ai, ah);
      gru8(h, ai, ah, a.bih2[col], a.bih2[128 + col], a.bih2[256 + col],
           a.bhh2[col], a.bhh2[128 + col], a.bhh2[256 + col], res2);
    }
    f32x4 res3[2];
    {
      f32x4 h[2], ai[2][3], ah[2][3];
      gru_unit(lds, 16, ctw, lane, a.wsp3, a.combp3, a.whhsp3, h, ai, ah);
      gru8(h, ai, ah, a.bih3[col], a.bih3[128 + col], a.bih3[256 + col],
           a.bhh3[col], a.bhh3[128 + col], a.bhh3[256 + col], res3);
    }
    #pragma unroll
    for (int rf = 0; rf < 2; ++rf)
      #pragma unroll
      for (int q = 0; q < 4; ++q) {
        int r = rbase + rf * 16 + lq + q;
        if (r < NN)
          a.out_a[(size_t)r * DD + col] = fmaxf((res2[rf][q] + res3[rf][q]) * 0.5f, 0.f);
      }
  } else {
    // ---- e1 -> out_b ----
    const int rbase = (bx - ROWT) * 32;

    #pragma unroll
    for (int i = 0; i < 2; ++i) {
      int f = wave * 2 + i;
      const short* src = (f & 8) ? a.agg1 : a.xb;
      int r = rbase + ((f >> 2) & 1) * 16 + (lane & 15);
      if (r >= NN) r = NN - 1;
      gl_lds16(src + (size_t)r * DD + (f & 3) * 32 + ((lane >> 4) << 3), lds + f * 512);
    }
    __syncthreads();

    f32x4 h[2], ai[2][3], ah[2][3];
    gru_unit(lds, 8, ctw, lane, a.wsp1, a.combp1, a.whhsp1, h, ai, ah);

    f32x4 res[2];
    gru8(h, ai, ah, a.bih1[col], a.bih1[128 + col], a.bih1[256 + col],
         a.bhh1[col], a.bhh1[128 + col], a.bhh1[256 + col], res);
    #pragma unroll
    for (int rf = 0; rf < 2; ++rf)
      #pragma unroll
      for (int q = 0; q < 4; ++q) {
        int r = rbase + rf * 16 + lq + q;
        if (r < NN) a.out_b[(size_t)r * DD + col] = fmaxf(res[rf][q], 0.f);
      }
  }
}

extern "C" void kernel_launch(void* const* d_in, const int* in_sizes, int n_in,
                              void* d_out, int out_size, void* d_ws, size_t ws_size,
                              hipStream_t stream) {
  const float* x_a = (const float*)d_in[0];
  const float* x_b = (const float*)d_in[1];
  const int* edges[3] = {(const int*)d_in[2], (const int*)d_in[3], (const int*)d_in[4]};
  const float *Ws[3], *Wt[3], *wih[3], *whh[3], *bih[3], *bhh[3];
  for (int e = 0; e < 3; ++e) {
    int b = 5 + e * 6;
    Ws[e]  = (const float*)d_in[b + 0];
    Wt[e]  = (const float*)d_in[b + 1];
    wih[e] = (const float*)d_in[b + 2];
    whh[e] = (const float*)d_in[b + 3];
    bih[e] = (const float*)d_in[b + 4];
    bhh[e] = (const float*)d_in[b + 5];
  }

  // workspace layout (~74.4 MB)
  char* ws = (char*)d_ws;
  short* xa_bf  = (short*)ws;                        // 12.8 MB
  short* xb_bf  = (short*)(ws + 12800000);           // 12.8 MB
  short* aggX   = (short*)(ws + 25600000);           // 3 x 12.8 MB
  int*   offs   = (int*)(ws + 64000000);             // 3 x 200 KB
  u16*   bucket = (u16*)(ws + 64600000);             // 3 x 1 MB
  uint32_t* cbkt= (uint32_t*)(ws + 67600000);        // 3 x 2 MB
  short* pk     = (short*)(ws + 73600000);           // 3 x 224 KB
  int*   ccnt   = (int*)(ws + 74300000);             // 3 x NBIN
  int*   cstart = (int*)(ws + 74310000);
  int*   ccur   = (int*)(ws + 74320000);
  short *wsp[3], *combp[3], *whhsp[3];
  short* aggp[3];
  int* offsp[3]; u16* bktp[3]; uint32_t* cbktp[3];
  for (int e = 0; e < 3; ++e) {
    short* base = pk + (size_t)e * 114688;
    wsp[e] = base; combp[e] = base + 16384; whhsp[e] = base + 65536;
    aggp[e]  = aggX + (size_t)e * NN * DD;
    offsp[e] = offs + (size_t)e * 50000;
    bktp[e]  = bucket + (size_t)e * 500000;
    cbktp[e] = cbkt + (size_t)e * 500000;
  }

  // 0) zero coarse counts (before prep, which includes chist)
  (void)hipMemsetAsync(ccnt, 0, 3 * NBIN * sizeof(int), stream);

  // 1) prep: convert + comb + pack + chist in ONE dispatch
  PrepArgs pa;
  pa.csrc[0] = x_a; pa.cdst[0] = xa_bf;
  pa.csrc[1] = x_b; pa.cdst[1] = xb_bf;
  for (int e = 0; e < 3; ++e) {
    pa.A[e] = wih[e];     pa.B[e] = Wt[e]; pa.pout[e] = combp[e];
    pa.A[3 + e] = whh[e]; pa.B[3 + e] = Ws[e]; pa.pout[3 + e] = whhsp[e];
    pa.psrc[e] = Ws[e];   pa.pdst[e] = wsp[e];
    pa.edge[e] = edges[e];
  }
  pa.ccnt = ccnt;
  hipLaunchKernelGGL(k_prep, dim3(6250, 14), dim3(256), 0, stream, pa);

  // 2) CSR: scan -> coarse bin -> fine sort
  CsrArgs ca;
  for (int e = 0; e < 3; ++e) {
    ca.edge[e] = edges[e];
    ca.cbkt[e] = cbktp[e];
    ca.offs[e] = offsp[e];
    ca.bucket[e] = bktp[e];
  }
  ca.ccnt = ccnt; ca.cstart = cstart; ca.ccur = ccur;
  hipLaunchKernelGGL(k_cscan, dim3(1), dim3(384), 0, stream, ca);
  hipLaunchKernelGGL(k_cbin, dim3((EE + 4095) / 4096, 3), dim3(256), 0, stream, ca);
  hipLaunchKernelGGL(k_fsort, dim3(NBIN, 3), dim3(256), 0, stream, ca);

  // 3) gather all 3 types
  GArgs ga;
  const short* srcb[3] = {xa_bf, xb_bf, xb_bf};
  for (int e = 0; e < 3; ++e) {
    ga.offs[e] = offsp[e]; ga.bkt[e] = bktp[e];
    ga.xsrc[e] = srcb[e];  ga.agg[e] = aggp[e];
  }
  hipLaunchKernelGGL(k_gather, dim3(ROWT, 3), dim3(256), 0, stream, ga);

  // 4) merged GEMM+GRU: one dispatch; e2+e3 serial full-width blocks, then e1 blocks
  float* out_a = (float*)d_out;
  float* out_b = (float*)d_out + (size_t)NN * DD;

  GGArgs gg;
  gg.agg1 = aggp[0]; gg.agg2 = aggp[1]; gg.agg3 = aggp[2];
  gg.xa = xa_bf; gg.xb = xb_bf;
  gg.wsp1 = wsp[0]; gg.combp1 = combp[0]; gg.whhsp1 = whhsp[0];
  gg.wsp2 = wsp[1]; gg.combp2 = combp[1]; gg.whhsp2 = whhsp[1];
  gg.wsp3 = wsp[2]; gg.combp3 = combp[2]; gg.whhsp3 = whhsp[2];
  gg.bih1 = bih[0]; gg.bhh1 = bhh[0];
  gg.bih2 = bih[1]; gg.bhh2 = bhh[1];
  gg.bih3 = bih[2]; gg.bhh3 = bhh[2];
  gg.out_a = out_a; gg.out_b = out_b;
  hipLaunchKernelGGL(k_ggru, dim3(ROWT * 2), dim3(512), 0, stream, gg);
}

// Round 25
// 205.109 us; speedup vs baseline: 1.0999x; 1.0999x over previous
//
#include <hip/hip_runtime.h>
#include <hip/hip_bf16.h>
#include <stdint.h>
#include <math.h>

#define NN 50000
#define DD 128
#define EE 500000
#define ROWT 1563   // ceil(NN/32)
#define NBIN 98     // ceil(NN/512) coarse bins
#define CHB 245     // ceil(EE/2048)

typedef __attribute__((ext_vector_type(8))) short bfx8;
typedef __attribute__((ext_vector_type(4))) short bfx4;
typedef __attribute__((ext_vector_type(4))) float f32x4;
typedef __attribute__((ext_vector_type(4))) int i32x4;
typedef unsigned short u16;

static __device__ __forceinline__ short f2bf(float f) {
  union { float f; uint32_t u; } v; v.f = f;
  uint32_t r = (v.u + 0x7fffu + ((v.u >> 16) & 1u)) >> 16;
  return (short)r;
}
static __device__ __forceinline__ float bf2f(short b) {
  union { uint32_t u; float f; } v; v.u = ((uint32_t)(uint16_t)b) << 16;
  return v.f;
}

// async global->LDS, 16B per lane; LDS dest = wave-uniform base + lane*16
static __device__ __forceinline__ void gl_lds16(const short* g, short* l) {
  __builtin_amdgcn_global_load_lds(
      (const __attribute__((address_space(1))) unsigned int*)g,
      (__attribute__((address_space(3))) unsigned int*)l, 16, 0, 0);
}

// B-fragment from packed weights: [ct][ks][64 lanes][8]
static __device__ __forceinline__ bfx8 load_pk(const short* p, int ct, int ks, int lane) {
  return *reinterpret_cast<const bfx8*>(p + ((((size_t)ct * 4 + ks) * 64 + lane) << 3));
}

// ---------------- prep: convert(0,1) | comb(2..7) | pack Ws(8..10) | chist(11..13) ----------------
struct PrepArgs {
  const float* csrc[2]; short* cdst[2];
  const float* A[6]; const float* B[6]; short* pout[6];
  const float* psrc[3]; short* pdst[3];
  const int* edge[3]; int* ccnt;
};

__global__ __launch_bounds__(256) void k_prep(PrepArgs p) {
  const int y = blockIdx.y;
  if (y < 2) {
    int i = (blockIdx.x * 256 + threadIdx.x) * 4;
    if (i >= NN * DD) return;
    f32x4 v = *reinterpret_cast<const f32x4*>(p.csrc[y] + i);
    bfx4 o;
    o[0]=f2bf(v[0]); o[1]=f2bf(v[1]); o[2]=f2bf(v[2]); o[3]=f2bf(v[3]);
    *reinterpret_cast<bfx4*>(p.cdst[y] + i) = o;
  } else if (y < 8) {
    if (blockIdx.x >= 192) return;
    const int e = y - 2;
    const float* A = p.A[e];
    const float* B = p.B[e];
    int tid = blockIdx.x * 256 + threadIdx.x;   // 49152 = 384*128
    int i = tid >> 7, j = tid & 127;            // P[i][j]
    float acc = 0.f;
    #pragma unroll 4
    for (int k = 0; k < 128; ++k) acc += A[i * 128 + k] * B[k * 128 + j];
    int ct = i >> 4;
    int lane = (i & 15) | ((((j & 31) >> 3)) << 4);
    int ks = j >> 5;
    int elem = j & 7;
    p.pout[e][(((size_t)(ct * 4 + ks) * 64 + lane) << 3) + elem] = f2bf(acc);
  } else if (y < 11) {
    if (blockIdx.x >= 8) return;
    const int jb = y - 8;
    int tid = blockIdx.x * 256 + threadIdx.x;   // < 2048 (nct=8)
    int lane = tid & 63, ks = (tid >> 6) & 3, ct = tid >> 8;
    const float* s = p.psrc[jb] + (size_t)(ct * 16 + (lane & 15)) * 128 + ks * 32 + ((lane >> 4) << 3);
    bfx8 o;
    #pragma unroll
    for (int i = 0; i < 8; ++i) o[i] = f2bf(s[i]);
    *reinterpret_cast<bfx8*>(p.pdst[jb] + ((size_t)tid << 3)) = o;
  } else {
    // coarse hist with LDS pre-aggregation
    if (blockIdx.x >= CHB) return;
    const int t = y - 11, tid = threadIdx.x;
    __shared__ int cnt[NBIN];
    for (int b = tid; b < NBIN; b += 256) cnt[b] = 0;
    __syncthreads();
    const int* ed = p.edge[t];
    int base = blockIdx.x * 2048;
    #pragma unroll
    for (int m = 0; m < 8; ++m) {
      int i = base + m * 256 + tid;
      if (i < EE) atomicAdd(&cnt[ed[EE + i] >> 9], 1);
    }
    __syncthreads();
    for (int b = tid; b < NBIN; b += 256)
      if (cnt[b]) atomicAdd(&p.ccnt[t * NBIN + b], cnt[b]);
  }
}

// ---------------- CSR build via two-level counting sort ----------------
struct CsrArgs {
  const int* edge[3];
  int* ccnt;      // [3][NBIN]
  int* cstart;    // [3][NBIN]
  int* ccur;      // [3][NBIN]
  uint32_t* cbkt[3];
  int* offs[3];
  u16* bucket[3];
};

// coarse scan: 3 types x NBIN (tiny)
__global__ __launch_bounds__(384) void k_cscan(CsrArgs a) {
  __shared__ int buf[3][128];
  int ty = threadIdx.x >> 7;       // 0..2
  int i = threadIdx.x & 127;
  int v = (i < NBIN) ? a.ccnt[ty * NBIN + i] : 0;
  buf[ty][i] = v;
  __syncthreads();
  for (int off = 1; off < 128; off <<= 1) {
    int tv = (i >= off) ? buf[ty][i - off] : 0;
    __syncthreads();
    buf[ty][i] += tv;
    __syncthreads();
  }
  if (i < NBIN) {
    int excl = buf[ty][i] - v;
    a.cstart[ty * NBIN + i] = excl;
    a.ccur[ty * NBIN + i] = excl;
  }
}

// coarse bin: per-block LDS count -> reserve -> burst write u32 entries
__global__ __launch_bounds__(256) void k_cbin(CsrArgs a) {
  const int t = blockIdx.y, tid = threadIdx.x;
  __shared__ int cnt[NBIN], cur[NBIN];
  for (int b = tid; b < NBIN; b += 256) cnt[b] = 0;
  __syncthreads();
  const int* ed = a.edge[t];
  int base = blockIdx.x * 4096;
  #pragma unroll
  for (int m = 0; m < 16; ++m) {
    int i = base + m * 256 + tid;
    if (i < EE) atomicAdd(&cnt[ed[EE + i] >> 9], 1);
  }
  __syncthreads();
  for (int b = tid; b < NBIN; b += 256)
    cur[b] = cnt[b] ? atomicAdd(&a.ccur[t * NBIN + b], cnt[b]) : 0;
  __syncthreads();
  uint32_t* cb = a.cbkt[t];
  #pragma unroll
  for (int m = 0; m < 16; ++m) {
    int i = base + m * 256 + tid;
    if (i < EE) {
      int tg = ed[EE + i];
      int b = tg >> 9;
      int pos = atomicAdd(&cur[b], 1);
      cb[pos] = (uint32_t)ed[i] | ((uint32_t)(tg & 511) << 20);
    }
  }
}

// fine sort: one block per coarse bin; counting sort by row; writes offs + u16 bucket
__global__ __launch_bounds__(256) void k_fsort(CsrArgs a) {
  const int t = blockIdx.y, bin = blockIdx.x, tid = threadIdx.x;
  __shared__ int rc[512], rcur[512], sb[256];
  int s0 = a.cstart[t * NBIN + bin];
  int cntb = a.ccnt[t * NBIN + bin];
  rc[tid] = 0; rc[tid + 256] = 0;
  __syncthreads();
  const uint32_t* cb = a.cbkt[t];
  for (int i = tid; i < cntb; i += 256) atomicAdd(&rc[cb[s0 + i] >> 20], 1);
  __syncthreads();
  int A = rc[2 * tid], B = rc[2 * tid + 1], s = A + B;
  sb[tid] = s;
  __syncthreads();
  for (int off = 1; off < 256; off <<= 1) {
    int v = (tid >= off) ? sb[tid - off] : 0;
    __syncthreads();
    sb[tid] += v;
    __syncthreads();
  }
  int excl = sb[tid] - s;
  rcur[2 * tid] = s0 + excl;
  rcur[2 * tid + 1] = s0 + excl + A;
  int rows0 = bin << 9;
  int nr = NN - rows0; if (nr > 512) nr = 512;
  if (2 * tid < nr)     a.offs[t][rows0 + 2 * tid]     = s0 + excl + A;
  if (2 * tid + 1 < nr) a.offs[t][rows0 + 2 * tid + 1] = s0 + excl + A + B;
  __syncthreads();
  u16* fb = a.bucket[t];
  for (int i = tid; i < cntb; i += 256) {
    uint32_t e = cb[s0 + i];
    int pos = atomicAdd(&rcur[e >> 20], 1);
    fb[pos] = (u16)e;          // src < 50000 < 2^16
  }
}

// ---------------- gather: aggX[row] = sum of x rows (bf16 out, deep unroll) ----------------
struct GArgs {
  const int* offs[3]; const u16* bkt[3];
  const short* xsrc[3]; short* agg[3];
};

__global__ __launch_bounds__(256) void k_gather(GArgs a) {
  const int ty = blockIdx.y;
  const int* __restrict__ offs = a.offs[ty];
  const u16* __restrict__ bucket = a.bkt[ty];
  const short* __restrict__ xsrc = a.xsrc[ty];
  short* __restrict__ agg = a.agg[ty];
  int tid = threadIdx.x;
  int row = blockIdx.x * 32 + (tid >> 3);
  if (row >= NN) return;
  int c0 = (tid & 7) * 16;
  int start = row ? offs[row - 1] : 0;
  int end = offs[row];
  f32x4 s0 = (f32x4)(0.f), s1 = (f32x4)(0.f), s2 = (f32x4)(0.f), s3 = (f32x4)(0.f);
  int i = start;
  for (; i + 8 <= end; i += 8) {
    const short* pp[8];
    #pragma unroll
    for (int m = 0; m < 8; ++m) pp[m] = xsrc + (size_t)bucket[i + m] * DD + c0;
    #pragma unroll
    for (int m = 0; m < 8; ++m) {
      bfx8 u = *reinterpret_cast<const bfx8*>(pp[m]);
      bfx8 v = *reinterpret_cast<const bfx8*>(pp[m] + 8);
      #pragma unroll
      for (int j = 0; j < 4; ++j) {
        s0[j] += bf2f(u[j]); s1[j] += bf2f(u[4+j]);
        s2[j] += bf2f(v[j]); s3[j] += bf2f(v[4+j]);
      }
    }
  }
  for (; i + 4 <= end; i += 4) {
    const short* pp[4];
    #pragma unroll
    for (int m = 0; m < 4; ++m) pp[m] = xsrc + (size_t)bucket[i + m] * DD + c0;
    #pragma unroll
    for (int m = 0; m < 4; ++m) {
      bfx8 u = *reinterpret_cast<const bfx8*>(pp[m]);
      bfx8 v = *reinterpret_cast<const bfx8*>(pp[m] + 8);
      #pragma unroll
      for (int j = 0; j < 4; ++j) {
        s0[j] += bf2f(u[j]); s1[j] += bf2f(u[4+j]);
        s2[j] += bf2f(v[j]); s3[j] += bf2f(v[4+j]);
      }
    }
  }
  for (; i < end; ++i) {
    const short* p = xsrc + (size_t)bucket[i] * DD + c0;
    bfx8 u = *reinterpret_cast<const bfx8*>(p), v = *reinterpret_cast<const bfx8*>(p + 8);
    #pragma unroll
    for (int j = 0; j < 4; ++j) {
      s0[j] += bf2f(u[j]); s1[j] += bf2f(u[4+j]);
      s2[j] += bf2f(v[j]); s3[j] += bf2f(v[4+j]);
    }
  }
  short* d = agg + (size_t)row * DD + c0;
  bfx8 o0, o1;
  #pragma unroll
  for (int j = 0; j < 4; ++j) {
    o0[j] = f2bf(s0[j]); o0[4+j] = f2bf(s1[j]);
    o1[j] = f2bf(s2[j]); o1[4+j] = f2bf(s3[j]);
  }
  *reinterpret_cast<bfx8*>(d) = o0;
  *reinterpret_cast<bfx8*>(d + 8) = o1;
}

// ---------------- GRU math + unit helpers ----------------
static __device__ __forceinline__ void gru8(const f32x4 h[2], const f32x4 ai[2][3],
                                            const f32x4 ah[2][3],
                                            float bir, float biz, float bin,
                                            float bhr, float bhz, float bhn,
                                            f32x4 res[2]) {
  #pragma unroll
  for (int rf = 0; rf < 2; ++rf)
    #pragma unroll
    for (int q = 0; q < 4; ++q) {
      float ir = ai[rf][0][q] + bir, iz = ai[rf][1][q] + biz, in = ai[rf][2][q] + bin;
      float hr = ah[rf][0][q] + bhr, hz = ah[rf][1][q] + bhz, hn = ah[rf][2][q] + bhn;
      float rr = __builtin_amdgcn_rcpf(1.f + __expf(-(ir + hr)));
      float zz = __builtin_amdgcn_rcpf(1.f + __expf(-(iz + hz)));
      float t2 = in + rr * hn;
      float nn = 1.f - 2.f * __builtin_amdgcn_rcpf(__expf(2.f * t2) + 1.f);   // tanh
      res[rf][q] = (1.f - zz) * nn + zz * h[rf][q];
    }
}

static __device__ __forceinline__ void gru_unit(
    const short* lds, int gbase, int ctw, int lane,
    const short* wsp, const short* combp, const short* whhsp,
    f32x4 (&h)[2], f32x4 (&ai)[2][3], f32x4 (&ah)[2][3]) {
  #pragma unroll
  for (int rf = 0; rf < 2; ++rf) {
    h[rf] = (f32x4)(0.f);
    #pragma unroll
    for (int g = 0; g < 3; ++g) { ai[rf][g] = (f32x4)(0.f); ah[rf][g] = (f32x4)(0.f); }
  }
  #pragma unroll
  for (int ks = 0; ks < 4; ++ks) {
    bfx8 x0 = *reinterpret_cast<const bfx8*>(lds + (0 + ks) * 512 + lane * 8);
    bfx8 x1 = *reinterpret_cast<const bfx8*>(lds + (4 + ks) * 512 + lane * 8);
    bfx8 g0 = *reinterpret_cast<const bfx8*>(lds + (gbase + ks) * 512 + lane * 8);
    bfx8 g1 = *reinterpret_cast<const bfx8*>(lds + (gbase + 4 + ks) * 512 + lane * 8);
    bfx8 bws = load_pk(wsp, ctw, ks, lane);
    h[0] = __builtin_amdgcn_mfma_f32_16x16x32_bf16(g0, bws, h[0], 0, 0, 0);
    h[1] = __builtin_amdgcn_mfma_f32_16x16x32_bf16(g1, bws, h[1], 0, 0, 0);
    #pragma unroll
    for (int g = 0; g < 3; ++g) {
      int ct = g * 8 + ctw;
      bfx8 bi = load_pk(combp, ct, ks, lane);
      bfx8 bh = load_pk(whhsp, ct, ks, lane);
      ai[0][g] = __builtin_amdgcn_mfma_f32_16x16x32_bf16(x0, bi, ai[0][g], 0, 0, 0);
      ai[1][g] = __builtin_amdgcn_mfma_f32_16x16x32_bf16(x1, bi, ai[1][g], 0, 0, 0);
      ah[0][g] = __builtin_amdgcn_mfma_f32_16x16x32_bf16(g0, bh, ah[0][g], 0, 0, 0);
      ah[1][g] = __builtin_amdgcn_mfma_f32_16x16x32_bf16(g1, bh, ah[1][g], 0, 0, 0);
    }
  }
}

// ---------------- merged ggru: blocks [0, 2*ROWT) = e2||e3 -> out_a; [2*ROWT, 3*ROWT) = e1 -> out_b ----------------
struct GGArgs {
  const short* agg1; const short* agg2; const short* agg3;
  const short* xa; const short* xb;
  const short* wsp1; const short* combp1; const short* whhsp1;
  const short* wsp2; const short* combp2; const short* whhsp2;
  const short* wsp3; const short* combp3; const short* whhsp3;
  const float* bih1; const float* bhh1;
  const float* bih2; const float* bhh2;
  const float* bih3; const float* bhh3;
  float* out_a; float* out_b;
};

__global__ __launch_bounds__(512) void k_ggru(GGArgs a) {
  __shared__ short lds[24 * 512];
  __shared__ float r3buf[32 * 68];     // dedicated: no aliasing barrier needed
  const int wave = threadIdx.x >> 6, lane = threadIdx.x & 63;
  const int bx = blockIdx.x;

  if (bx < 2 * ROWT) {
    // XCD-pair swizzle: pair-mates are 8 apart in bx -> same XCD (bx%8), so the
    // duplicate 24KB stage of colblk-partner hits the local L2.
    int pair, colblk;
    if (bx < 3120) {                 // 195 groups of 16
      pair = (bx >> 4) * 8 + (bx & 7);
      colblk = (bx >> 3) & 1;
    } else {                         // tail: 6 blocks -> pairs 1560..1562
      pair = 1560 + ((bx - 3120) >> 1);
      colblk = (bx - 3120) & 1;
    }
    const int rbase = pair * 32;
    const int unit = wave >> 2;
    const int ctw = colblk * 4 + (wave & 3);

    #pragma unroll
    for (int i = 0; i < 3; ++i) {
      int f = wave * 3 + i;
      const short* src = (f < 8) ? a.xa : ((f < 16) ? a.agg2 : a.agg3);
      int r = rbase + ((f >> 2) & 1) * 16 + (lane & 15);
      if (r >= NN) r = NN - 1;
      gl_lds16(src + (size_t)r * DD + (f & 3) * 32 + ((lane >> 4) << 3), lds + f * 512);
    }
    __syncthreads();

    const short* wspU   = unit ? a.wsp3   : a.wsp2;
    const short* combpU = unit ? a.combp3 : a.combp2;
    const short* whhspU = unit ? a.whhsp3 : a.whhsp2;
    const float* bihU   = unit ? a.bih3   : a.bih2;
    const float* bhhU   = unit ? a.bhh3   : a.bhh2;
    const int gbase = unit ? 16 : 8;

    f32x4 h[2], ai[2][3], ah[2][3];
    gru_unit(lds, gbase, ctw, lane, wspU, combpU, whhspU, h, ai, ah);

    const int col = ctw * 16 + (lane & 15);
    const int cl = (wave & 3) * 16 + (lane & 15);
    const int lq = (lane >> 4) << 2;
    f32x4 res[2];
    gru8(h, ai, ah, bihU[col], bihU[128 + col], bihU[256 + col],
         bhhU[col], bhhU[128 + col], bhhU[256 + col], res);

    if (unit == 1) {
      #pragma unroll
      for (int rf = 0; rf < 2; ++rf)
        #pragma unroll
        for (int q = 0; q < 4; ++q)
          r3buf[(rf * 16 + lq + q) * 68 + cl] = res[rf][q];
    }
    __syncthreads();
    if (unit == 0) {
      #pragma unroll
      for (int rf = 0; rf < 2; ++rf)
        #pragma unroll
        for (int q = 0; q < 4; ++q) {
          int r = rbase + rf * 16 + lq + q;
          if (r < NN) {
            float r3 = r3buf[(rf * 16 + lq + q) * 68 + cl];
            a.out_a[(size_t)r * DD + col] = fmaxf((res[rf][q] + r3) * 0.5f, 0.f);
          }
        }
    }
  } else {
    // ---- e1 -> out_b ----
    const int rbase = (bx - 2 * ROWT) * 32;
    const int ctw = wave;

    #pragma unroll
    for (int i = 0; i < 2; ++i) {
      int f = wave * 2 + i;
      const short* src = (f & 8) ? a.agg1 : a.xb;
      int r = rbase + ((f >> 2) & 1) * 16 + (lane & 15);
      if (r >= NN) r = NN - 1;
      gl_lds16(src + (size_t)r * DD + (f & 3) * 32 + ((lane >> 4) << 3), lds + f * 512);
    }
    __syncthreads();

    f32x4 h[2], ai[2][3], ah[2][3];
    gru_unit(lds, 8, ctw, lane, a.wsp1, a.combp1, a.whhsp1, h, ai, ah);

    const int col = ctw * 16 + (lane & 15);
    f32x4 res[2];
    gru8(h, ai, ah, a.bih1[col], a.bih1[128 + col], a.bih1[256 + col],
         a.bhh1[col], a.bhh1[128 + col], a.bhh1[256 + col], res);
    const int lq = (lane >> 4) << 2;
    #pragma unroll
    for (int rf = 0; rf < 2; ++rf)
      #pragma unroll
      for (int q = 0; q < 4; ++q) {
        int r = rbase + rf * 16 + lq + q;
        if (r < NN) a.out_b[(size_t)r * DD + col] = fmaxf(res[rf][q], 0.f);
      }
  }
}

extern "C" void kernel_launch(void* const* d_in, const int* in_sizes, int n_in,
                              void* d_out, int out_size, void* d_ws, size_t ws_size,
                              hipStream_t stream) {
  const float* x_a = (const float*)d_in[0];
  const float* x_b = (const float*)d_in[1];
  const int* edges[3] = {(const int*)d_in[2], (const int*)d_in[3], (const int*)d_in[4]};
  const float *Ws[3], *Wt[3], *wih[3], *whh[3], *bih[3], *bhh[3];
  for (int e = 0; e < 3; ++e) {
    int b = 5 + e * 6;
    Ws[e]  = (const float*)d_in[b + 0];
    Wt[e]  = (const float*)d_in[b + 1];
    wih[e] = (const float*)d_in[b + 2];
    whh[e] = (const float*)d_in[b + 3];
    bih[e] = (const float*)d_in[b + 4];
    bhh[e] = (const float*)d_in[b + 5];
  }

  // workspace layout (~74.4 MB)
  char* ws = (char*)d_ws;
  short* xa_bf  = (short*)ws;                        // 12.8 MB
  short* xb_bf  = (short*)(ws + 12800000);           // 12.8 MB
  short* aggX   = (short*)(ws + 25600000);           // 3 x 12.8 MB
  int*   offs   = (int*)(ws + 64000000);             // 3 x 200 KB
  u16*   bucket = (u16*)(ws + 64600000);             // 3 x 1 MB
  uint32_t* cbkt= (uint32_t*)(ws + 67600000);        // 3 x 2 MB
  short* pk     = (short*)(ws + 73600000);           // 3 x 224 KB
  int*   ccnt   = (int*)(ws + 74300000);             // 3 x NBIN
  int*   cstart = (int*)(ws + 74310000);
  int*   ccur   = (int*)(ws + 74320000);
  short *wsp[3], *combp[3], *whhsp[3];
  short* aggp[3];
  int* offsp[3]; u16* bktp[3]; uint32_t* cbktp[3];
  for (int e = 0; e < 3; ++e) {
    short* base = pk + (size_t)e * 114688;
    wsp[e] = base; combp[e] = base + 16384; whhsp[e] = base + 65536;
    aggp[e]  = aggX + (size_t)e * NN * DD;
    offsp[e] = offs + (size_t)e * 50000;
    bktp[e]  = bucket + (size_t)e * 500000;
    cbktp[e] = cbkt + (size_t)e * 500000;
  }

  // 0) zero coarse counts (before prep, which includes chist)
  (void)hipMemsetAsync(ccnt, 0, 3 * NBIN * sizeof(int), stream);

  // 1) prep: convert + comb + pack + chist in ONE dispatch
  PrepArgs pa;
  pa.csrc[0] = x_a; pa.cdst[0] = xa_bf;
  pa.csrc[1] = x_b; pa.cdst[1] = xb_bf;
  for (int e = 0; e < 3; ++e) {
    pa.A[e] = wih[e];     pa.B[e] = Wt[e]; pa.pout[e] = combp[e];
    pa.A[3 + e] = whh[e]; pa.B[3 + e] = Ws[e]; pa.pout[3 + e] = whhsp[e];
    pa.psrc[e] = Ws[e];   pa.pdst[e] = wsp[e];
    pa.edge[e] = edges[e];
  }
  pa.ccnt = ccnt;
  hipLaunchKernelGGL(k_prep, dim3(6250, 14), dim3(256), 0, stream, pa);

  // 2) CSR: scan -> coarse bin -> fine sort
  CsrArgs ca;
  for (int e = 0; e < 3; ++e) {
    ca.edge[e] = edges[e];
    ca.cbkt[e] = cbktp[e];
    ca.offs[e] = offsp[e];
    ca.bucket[e] = bktp[e];
  }
  ca.ccnt = ccnt; ca.cstart = cstart; ca.ccur = ccur;
  hipLaunchKernelGGL(k_cscan, dim3(1), dim3(384), 0, stream, ca);
  hipLaunchKernelGGL(k_cbin, dim3((EE + 4095) / 4096, 3), dim3(256), 0, stream, ca);
  hipLaunchKernelGGL(k_fsort, dim3(NBIN, 3), dim3(256), 0, stream, ca);

  // 3) gather all 3 types
  GArgs ga;
  const short* srcb[3] = {xa_bf, xb_bf, xb_bf};
  for (int e = 0; e < 3; ++e) {
    ga.offs[e] = offsp[e]; ga.bkt[e] = bktp[e];
    ga.xsrc[e] = srcb[e];  ga.agg[e] = aggp[e];
  }
  hipLaunchKernelGGL(k_gather, dim3(ROWT, 3), dim3(256), 0, stream, ga);

  // 4) merged GEMM+GRU: one dispatch, disjoint block ranges
  float* out_a = (float*)d_out;
  float* out_b = (float*)d_out + (size_t)NN * DD;

  GGArgs gg;
  gg.agg1 = aggp[0]; gg.agg2 = aggp[1]; gg.agg3 = aggp[2];
  gg.xa = xa_bf; gg.xb = xb_bf;
  gg.wsp1 = wsp[0]; gg.combp1 = combp[0]; gg.whhsp1 = whhsp[0];
  gg.wsp2 = wsp[1]; gg.combp2 = combp[1]; gg.whhsp2 = whhsp[1];
  gg.wsp3 = wsp[2]; gg.combp3 = combp[2]; gg.whhsp3 = whhsp[2];
  gg.bih1 = bih[0]; gg.bhh1 = bhh[0];
  gg.bih2 = bih[1]; gg.bhh2 = bhh[1];
  gg.bih3 = bih[2]; gg.bhh3 = bhh[2];
  gg.out_a = out_a; gg.out_b = out_b;
  hipLaunchKernelGGL(k_ggru, dim3(ROWT * 3), dim3(512), 0, stream, gg);
}